// Round 5
// baseline (789.028 us; speedup 1.0000x reference)
//
#include <hip/hip_runtime.h>

#define T_STEPS 1024
#define BATCH 2048
#define BTILE 8   // 8 batch rows/block -> 256 blocks -> 1 block/CU
#define HS 36     // LDS row stride in u32 words; 36 % 32 == 4 -> conflict-free b128 reads

typedef short short8 __attribute__((ext_vector_type(8)));
typedef float f32x4 __attribute__((ext_vector_type(4)));
typedef float f32x2 __attribute__((ext_vector_type(2)));

__device__ __forceinline__ float fast_rcp(float x) {
#if __has_builtin(__builtin_amdgcn_rcpf)
    return __builtin_amdgcn_rcpf(x);
#else
    return 1.0f / x;
#endif
}

__device__ __forceinline__ float fast_exp2(float x) {
#if __has_builtin(__builtin_amdgcn_exp2f)
    return __builtin_amdgcn_exp2f(x);
#else
    return exp2f(x);
#endif
}

__device__ __forceinline__ float sigf(float x) {
    return fast_rcp(1.0f + fast_exp2(-1.44269504f * x));
}

__device__ __forceinline__ f32x2 sigf2(f32x2 v) {
    f32x2 t = v * (-1.44269504f);
    f32x2 e = {fast_exp2(t[0]), fast_exp2(t[1])};
    e = e + 1.0f;
    return f32x2{fast_rcp(e[0]), fast_rcp(e[1])};
}

__device__ __forceinline__ float tanh_fast(float x) {
    float e = fast_exp2(2.88539008f * x);
    return 1.0f - 2.0f * fast_rcp(e + 1.0f);
}

__device__ __forceinline__ f32x2 tanh2(f32x2 v) {
    f32x2 t = v * 2.88539008f;
    f32x2 e = {fast_exp2(t[0]), fast_exp2(t[1])};
    e = e + 1.0f;
    f32x2 r = {fast_rcp(e[0]), fast_rcp(e[1])};
    return f32x2{1.0f, 1.0f} - 2.0f * r;
}

// float -> bf16 bits (RNE) — setup only
__device__ __forceinline__ unsigned f2bf(float x) {
    unsigned u = __float_as_uint(x);
    unsigned r = u + 0x7FFFu + ((u >> 16) & 1u);
    return r >> 16;
}
__device__ __forceinline__ float bf2f(unsigned b) {
    return __uint_as_float(b << 16);
}

__device__ __forceinline__ unsigned cvt_pk_bf16(float a, float b) {
    unsigned r;
    asm("v_cvt_pk_bf16_f32 %0, %1, %2" : "=v"(r) : "v"(a), "v"(b));
    return r;
}

// DPP conventions (HW-validated): 0x110+N: lane l <- lane l-N (row-16);
// 0x100+N: lane l <- lane l+N. bank_mask: unselected banks keep OLD dst.
__device__ __forceinline__ float dpp_pull8(float v) {   // lane l <- lane l+8
    return __int_as_float(__builtin_amdgcn_update_dpp(0, __float_as_int(v), 0x108, 0xf, 0xf, true));
}

// Per-step barrier without the vmcnt(0) drain __syncthreads() emits.
// All in-loop cross-wave traffic is LDS (lgkmcnt(0)+s_barrier orders it);
// global ops are write-only stores / same-thread prefetch.
__device__ __forceinline__ void step_barrier() {
    asm volatile("s_waitcnt lgkmcnt(0)\n\ts_barrier" ::: "memory");
}

// ===================== v13: 8-wave split-activation =========================
// v12's chain was latency-bound at 1 wave/SIMD. v13 runs 8 waves (512 thr):
// wave pair (2*wp, 2*wp+1) REDUNDANTLY computes the same 8 L1 MFMAs for unit
// group wp (matrix pipe was 13% busy — duplication is free) but SPLITS the
// expensive activation: hw=0 wave handles unit regs {0,1}, hw=1 regs {2,3},
// giving 1 cell/thread (vs 2) and TWO independent chains per SIMD to
// interleave. L2 recurrence stays deferred to lstm_l2_kernel (g1 workspace).
__global__ __launch_bounds__(512, 1)
void lstm_v13_kernel(const float* __restrict__ input,
                     const float* __restrict__ W_ih0,
                     const float* __restrict__ W_hh0,
                     const float* __restrict__ b_ih0,
                     const float* __restrict__ b_hh0,
                     const float* __restrict__ W_ih1,
                     float* __restrict__ g1ws)
{
    const int tid = threadIdx.x;
    const int w8  = tid >> 6;        // wave 0..7
    const int wp  = w8 >> 1;         // unit group 0..3
    const int hw  = w8 & 1;          // which reg pair {0,1} or {2,3}
    const int l   = tid & 63;
    const int q16 = l >> 4;
    const int n16 = l & 15;
    const int n8  = l & 7;           // batch
    const int hi8 = n16 >> 3;        // 0: even unit of pair, 1: odd
    const int u   = 16 * wp + 4 * q16 + 2 * hw + hi8;   // this thread's unit
    const int bbase = blockIdx.x * BTILE;

    __shared__ __align__(16) unsigned Hbuf[2][3][16][HS];   // 13.8 KB
    __shared__ float Xb[2][BTILE][65];                      // 4.2 KB

    for (int i = tid; i < 2 * 3 * 16 * HS; i += 512)
        reinterpret_cast<unsigned*>(Hbuf)[i] = 0u;

    // ---- L1 A-fragments for unit group wp (shared by the wave pair) ----
    short8 a1[4][2];
    #pragma unroll
    for (int g = 0; g < 4; ++g) {
        #pragma unroll
        for (int kt = 0; kt < 2; ++kt) {
            const float* p = W_hh0 + (size_t)(16 * (wp + 4 * g) + n16) * 64 + kt * 32 + q16 * 8;
            short8 a;
            #pragma unroll
            for (int j = 0; j < 8; ++j) a[j] = (short)f2bf(p[j]);
            a1[g][kt] = a;
        }
    }
    // ---- L2 A-fragments (hi/lo split), rows m>=4 zero; all waves load ----
    short8 a2h[2], a2l[2];
    #pragma unroll
    for (int kt = 0; kt < 2; ++kt) {
        short8 ah = {0,0,0,0,0,0,0,0}, al = {0,0,0,0,0,0,0,0};
        if (n16 < 4) {
            const float* p = W_ih1 + (size_t)n16 * 64 + kt * 32 + q16 * 8;
            #pragma unroll
            for (int j = 0; j < 8; ++j) {
                unsigned hb = f2bf(p[j]);
                ah[j] = (short)hb;
                al[j] = (short)f2bf(p[j] - bf2f(hb));
            }
        }
        a2h[kt] = ah; a2l[kt] = al;
    }

    // activation constants for this thread's single cell (unit u)
    float wg[4], bg[4];
    #pragma unroll
    for (int g = 0; g < 4; ++g) {
        int row = g * 64 + u;
        wg[g] = W_ih0[row];
        bg[g] = b_ih0[row] + b_hh0[row];
    }

    // ---- input staging: wave w8 covers batch row w8, lane l = col ----
    const float* rowptr = input + (size_t)(bbase + w8) * T_STEPS;
    Xb[0][w8][l] = rowptr[l];
    float xn = 0.0f;
    float c0 = 0.0f;

    __syncthreads();

    int par = 0;
    #pragma unroll 2
    for (int t = 0; t < T_STEPS; ++t) {
        if ((t & 63) == 0 && t + 64 < T_STEPS) xn = rowptr[t + 64 + l];
        const int cp = (t >> 6) & 1;

        // ---- B-fragments: h(t-1) ----
        const unsigned* Hrow = &Hbuf[par][0][n16][0];
        short8 hb0 = *reinterpret_cast<const short8*>(Hrow + 4 * q16);
        short8 hb1 = *reinterpret_cast<const short8*>(Hrow + 16 + 4 * q16);

        // ---- L1 MFMA (duplicated across the wave pair — matrix pipe idle) ----
        f32x4 accv[4];
        #pragma unroll
        for (int g = 0; g < 4; ++g) {
            f32x4 z = {0.0f, 0.0f, 0.0f, 0.0f};
            z = __builtin_amdgcn_mfma_f32_16x16x32_bf16(a1[g][0], hb0, z, 0, 0, 0);
            z = __builtin_amdgcn_mfma_f32_16x16x32_bf16(a1[g][1], hb1, z, 0, 0, 0);
            accv[g] = z;
        }

        // ---- shadow: g1 = W_ih1 @ c0n(t-1), fire-and-forget (rotates 8 waves) ----
        if (t > 0 && w8 == ((t - 1) & 7)) {
            const unsigned* Ch = &Hbuf[par][1][n16][0];
            const unsigned* Cl = &Hbuf[par][2][n16][0];
            short8 ch0 = *reinterpret_cast<const short8*>(Ch + 4 * q16);
            short8 ch1 = *reinterpret_cast<const short8*>(Ch + 16 + 4 * q16);
            short8 cl0 = *reinterpret_cast<const short8*>(Cl + 4 * q16);
            short8 cl1 = *reinterpret_cast<const short8*>(Cl + 16 + 4 * q16);
            f32x4 zA = {0.0f, 0.0f, 0.0f, 0.0f};
            f32x4 zB = {0.0f, 0.0f, 0.0f, 0.0f};
            zA = __builtin_amdgcn_mfma_f32_16x16x32_bf16(a2h[0], ch0, zA, 0, 0, 0);
            zB = __builtin_amdgcn_mfma_f32_16x16x32_bf16(a2l[1], ch1, zB, 0, 0, 0);
            zA = __builtin_amdgcn_mfma_f32_16x16x32_bf16(a2h[1], ch1, zA, 0, 0, 0);
            zB = __builtin_amdgcn_mfma_f32_16x16x32_bf16(a2h[0], cl0, zB, 0, 0, 0);
            zA = __builtin_amdgcn_mfma_f32_16x16x32_bf16(a2l[0], ch0, zA, 0, 0, 0);
            zB = __builtin_amdgcn_mfma_f32_16x16x32_bf16(a2h[1], cl1, zB, 0, 0, 0);
            f32x4 z = zA + zB;
            if (l < 8)
                *reinterpret_cast<f32x4*>(g1ws + ((size_t)(t - 1) * BATCH + bbase + l) * 4) = z;
        }

        // ---- gate select: this wave's reg pair {2hw, 2hw+1}; lanes n16<8
        //      keep reg 2hw (unit even), lanes n16>=8 pull reg 2hw+1 from
        //      lane l-8 (row_shr:8, banks 2,3). 4 DPP per thread, 1 cell. ----
        float v4[4];
        const int ra = 2 * hw;
        #pragma unroll
        for (int g = 0; g < 4; ++g) {
            int pa = __float_as_int(accv[g][ra]);
            pa = __builtin_amdgcn_update_dpp(pa, __float_as_int(accv[g][ra + 1]), 0x118, 0xf, 0xC, false);
            v4[g] = __int_as_float(pa);
        }

        // ---- layer-1 activation, 1 cell (batch n8, unit u) ----
        float x = Xb[cp][n8][t & 63];
        float gi = v4[0] + (x * wg[0] + bg[0]);
        float gf = v4[1] + (x * wg[1] + bg[1]);
        float gg = v4[2] + (x * wg[2] + bg[2]);
        float go = v4[3] + (x * wg[3] + bg[3]);

        float si = sigf(gi);
        float sf = sigf(gf);
        float tg = tanh_fast(gg);
        float c0n = sf * c0 + si * tg;
        c0 = c0n;
        float h0n = sigf(go) * tanh_fast(c0n);

        // ---- pack pair (even unit = own, odd = partner lane l+8) ----
        float ph = dpp_pull8(h0n);
        float pc = dpp_pull8(c0n);
        unsigned hword  = cvt_pk_bf16(h0n, ph);
        unsigned chword = cvt_pk_bf16(c0n, pc);
        float hi_own = bf2f(chword & 0xFFFFu);
        float lo_own = c0n - hi_own;
        float plo = dpp_pull8(lo_own);
        unsigned clword = cvt_pk_bf16(lo_own, plo);
        if (!hi8) {                               // even-unit lane writes the word
            const int widx = 8 * wp + 2 * q16 + hw;
            Hbuf[par ^ 1][0][n8][widx] = hword;
            Hbuf[par ^ 1][1][n8][widx] = chword;
            Hbuf[par ^ 1][2][n8][widx] = clword;
        }

        if ((t & 63) == 63 && t + 1 < T_STEPS) Xb[cp ^ 1][w8][l] = xn;

        step_barrier();
        par ^= 1;
    }

    // ---- epilogue: shadow g1 for step 1023 (wave 7) ----
    if (w8 == 7) {
        const unsigned* Ch = &Hbuf[par][1][n16][0];
        const unsigned* Cl = &Hbuf[par][2][n16][0];
        short8 ch0 = *reinterpret_cast<const short8*>(Ch + 4 * q16);
        short8 ch1 = *reinterpret_cast<const short8*>(Ch + 16 + 4 * q16);
        short8 cl0 = *reinterpret_cast<const short8*>(Cl + 4 * q16);
        short8 cl1 = *reinterpret_cast<const short8*>(Cl + 16 + 4 * q16);
        f32x4 zA = {0.0f, 0.0f, 0.0f, 0.0f};
        f32x4 zB = {0.0f, 0.0f, 0.0f, 0.0f};
        zA = __builtin_amdgcn_mfma_f32_16x16x32_bf16(a2h[0], ch0, zA, 0, 0, 0);
        zB = __builtin_amdgcn_mfma_f32_16x16x32_bf16(a2l[1], ch1, zB, 0, 0, 0);
        zA = __builtin_amdgcn_mfma_f32_16x16x32_bf16(a2h[1], ch1, zA, 0, 0, 0);
        zB = __builtin_amdgcn_mfma_f32_16x16x32_bf16(a2h[0], cl0, zB, 0, 0, 0);
        zA = __builtin_amdgcn_mfma_f32_16x16x32_bf16(a2l[0], ch0, zA, 0, 0, 0);
        zB = __builtin_amdgcn_mfma_f32_16x16x32_bf16(a2h[1], cl1, zB, 0, 0, 0);
        f32x4 z = zA + zB;
        if (l < 8)
            *reinterpret_cast<f32x4*>(g1ws + ((size_t)(T_STEPS - 1) * BATCH + bbase + l) * 4) = z;
    }
}

// ===================== phase 2: scalar L2 recurrence ========================
// 2048 independent chains: 32 blocks x 64 threads (32 CUs engaged) with an
// 8-deep static-indexed prefetch ring (unroll-8 keeps t&7 compile-time so
// the ring stays in registers — rule #20). g1 reads coalesced ([t][batch]).
__global__ __launch_bounds__(64)
void lstm_l2_kernel(const float* __restrict__ g1ws,
                    const float* __restrict__ W_hh1,
                    const float* __restrict__ b_ih1,
                    const float* __restrict__ b_hh1,
                    float* __restrict__ out)
{
    const int b = blockIdx.x * 64 + threadIdx.x;
    float w1[4], bb[4];
    #pragma unroll
    for (int g = 0; g < 4; ++g) { w1[g] = W_hh1[g]; bb[g] = b_ih1[g] + b_hh1[g]; }

    const f32x4* gp = reinterpret_cast<const f32x4*>(g1ws) + b;
    float* orow = out + (size_t)b * T_STEPS;
    float h1 = 0.0f, c1 = 0.0f;

    f32x4 zb[8];
    #pragma unroll
    for (int d = 0; d < 8; ++d) zb[d] = gp[(size_t)d * BATCH];

    #pragma unroll 8
    for (int t = 0; t < T_STEPS; ++t) {
        f32x4 z = zb[t & 7];
        if (t + 8 < T_STEPS) zb[t & 7] = gp[(size_t)(t + 8) * BATCH];
        float gi = z[0] + bb[0] + h1 * w1[0];
        float gf = z[1] + bb[1] + h1 * w1[1];
        float gg = z[2] + bb[2] + h1 * w1[2];
        float go = z[3] + bb[3] + h1 * w1[3];
        float c1n = sigf(gf) * c1 + sigf(gi) * tanh_fast(gg);
        c1 = c1n;
        h1 = sigf(go) * tanh_fast(c1n);
        orow[t] = c1n;
    }
}

// ===================== fallback (v11, self-contained) =======================
__global__ __launch_bounds__(256, 1)
void lstm_v11_kernel(const float* __restrict__ input,
                     const float* __restrict__ W_ih0,
                     const float* __restrict__ W_hh0,
                     const float* __restrict__ b_ih0,
                     const float* __restrict__ b_hh0,
                     const float* __restrict__ W_ih1,
                     const float* __restrict__ W_hh1,
                     const float* __restrict__ b_ih1,
                     const float* __restrict__ b_hh1,
                     float* __restrict__ out)
{
    const int tid = threadIdx.x;
    const int w   = tid >> 6;
    const int l   = tid & 63;
    const int q16 = l >> 4;
    const int n16 = l & 15;
    const int n8  = l & 7;
    const int hi8 = n16 >> 3;
    const int ua  = 16 * w + 4 * q16 + 2 * hi8;
    const int bbase = blockIdx.x * BTILE;

    __shared__ __align__(16) unsigned Hbuf[2][3][16][HS];
    __shared__ float Xb[2][BTILE][65];
    __shared__ float Lst[16];

    for (int i = tid; i < 2 * 3 * 16 * HS; i += 256)
        reinterpret_cast<unsigned*>(Hbuf)[i] = 0u;
    if (tid < 16) Lst[tid] = 0.0f;

    short8 a1[4][2];
    #pragma unroll
    for (int g = 0; g < 4; ++g) {
        #pragma unroll
        for (int kt = 0; kt < 2; ++kt) {
            const float* p = W_hh0 + (size_t)(16 * (w + 4 * g) + n16) * 64 + kt * 32 + q16 * 8;
            short8 a;
            #pragma unroll
            for (int j = 0; j < 8; ++j) a[j] = (short)f2bf(p[j]);
            a1[g][kt] = a;
        }
    }
    short8 a2h[2], a2l[2];
    #pragma unroll
    for (int kt = 0; kt < 2; ++kt) {
        short8 ah = {0,0,0,0,0,0,0,0}, al = {0,0,0,0,0,0,0,0};
        if (n16 < 4) {
            const float* p = W_ih1 + (size_t)n16 * 64 + kt * 32 + q16 * 8;
            #pragma unroll
            for (int j = 0; j < 8; ++j) {
                unsigned hb = f2bf(p[j]);
                ah[j] = (short)hb;
                al[j] = (short)f2bf(p[j] - bf2f(hb));
            }
        }
        a2h[kt] = ah; a2l[kt] = al;
    }

    f32x2 wg2[4], bg2[4];
    #pragma unroll
    for (int g = 0; g < 4; ++g) {
        int rA = g * 64 + ua;
        int rB = rA + 1;
        wg2[g] = f32x2{W_ih0[rA], W_ih0[rB]};
        bg2[g] = f32x2{b_ih0[rA] + b_hh0[rA], b_ih0[rB] + b_hh0[rB]};
    }
    float whh1v[4], b1v[4];
    #pragma unroll
    for (int g = 0; g < 4; ++g) { whh1v[g] = W_hh1[g]; b1v[g] = b_ih1[g] + b_hh1[g]; }

    const int xr = tid >> 5;
    const int xc = tid & 31;
    const float* rowptr = input + (size_t)(bbase + xr) * T_STEPS;
    Xb[0][xr][xc]      = rowptr[xc];
    Xb[0][xr][xc + 32] = rowptr[xc + 32];
    float xnA = 0.0f, xnB = 0.0f;
    f32x2 c02 = {0.0f, 0.0f};

    __syncthreads();

    int par = 0;
    #pragma unroll 2
    for (int t = 0; t < T_STEPS; ++t) {
        if ((t & 63) == 0 && t + 64 < T_STEPS) {
            xnA = rowptr[t + 64 + xc];
            xnB = rowptr[t + 64 + xc + 32];
        }
        const int cp = (t >> 6) & 1;

        const unsigned* Hrow = &Hbuf[par][0][n16][0];
        short8 hb0 = *reinterpret_cast<const short8*>(Hrow + 4 * q16);
        short8 hb1 = *reinterpret_cast<const short8*>(Hrow + 16 + 4 * q16);

        f32x4 accv[4];
        #pragma unroll
        for (int g = 0; g < 4; ++g) {
            f32x4 z = {0.0f, 0.0f, 0.0f, 0.0f};
            z = __builtin_amdgcn_mfma_f32_16x16x32_bf16(a1[g][0], hb0, z, 0, 0, 0);
            z = __builtin_amdgcn_mfma_f32_16x16x32_bf16(a1[g][1], hb1, z, 0, 0, 0);
            accv[g] = z;
        }

        if (t > 0 && w == ((t - 1) & 3)) {
            const unsigned* Ch = &Hbuf[par][1][n16][0];
            const unsigned* Cl = &Hbuf[par][2][n16][0];
            short8 ch0 = *reinterpret_cast<const short8*>(Ch + 4 * q16);
            short8 ch1 = *reinterpret_cast<const short8*>(Ch + 16 + 4 * q16);
            short8 cl0 = *reinterpret_cast<const short8*>(Cl + 4 * q16);
            short8 cl1 = *reinterpret_cast<const short8*>(Cl + 16 + 4 * q16);
            float h1p = Lst[n8], c1p = Lst[8 + n8];
            f32x4 zA = {0.0f, 0.0f, 0.0f, 0.0f};
            f32x4 zB = {0.0f, 0.0f, 0.0f, 0.0f};
            zA = __builtin_amdgcn_mfma_f32_16x16x32_bf16(a2h[0], ch0, zA, 0, 0, 0);
            zB = __builtin_amdgcn_mfma_f32_16x16x32_bf16(a2l[1], ch1, zB, 0, 0, 0);
            zA = __builtin_amdgcn_mfma_f32_16x16x32_bf16(a2h[1], ch1, zA, 0, 0, 0);
            zB = __builtin_amdgcn_mfma_f32_16x16x32_bf16(a2h[0], cl0, zB, 0, 0, 0);
            zA = __builtin_amdgcn_mfma_f32_16x16x32_bf16(a2l[0], ch0, zA, 0, 0, 0);
            zB = __builtin_amdgcn_mfma_f32_16x16x32_bf16(a2h[1], cl1, zB, 0, 0, 0);
            f32x4 z = zA + zB;
            float g1i = z[0] + b1v[0] + h1p * whh1v[0];
            float g1f = z[1] + b1v[1] + h1p * whh1v[1];
            float g1g = z[2] + b1v[2] + h1p * whh1v[2];
            float g1o = z[3] + b1v[3] + h1p * whh1v[3];
            float c1n = sigf(g1f) * c1p + sigf(g1i) * tanh_fast(g1g);
            float h1n = sigf(g1o) * tanh_fast(c1n);
            if (l < BTILE) {
                out[(size_t)(bbase + l) * T_STEPS + (t - 1)] = c1n;
                Lst[l] = h1n;
                Lst[8 + l] = c1n;
            }
        }

        float vA[4], vB[4];
        #pragma unroll
        for (int g = 0; g < 4; ++g) {
            int pa = __float_as_int(accv[g][0]);
            pa = __builtin_amdgcn_update_dpp(pa, __float_as_int(accv[g][2]), 0x118, 0xf, 0xC, false);
            int pb = __float_as_int(accv[g][1]);
            pb = __builtin_amdgcn_update_dpp(pb, __float_as_int(accv[g][3]), 0x118, 0xf, 0xC, false);
            vA[g] = __int_as_float(pa);
            vB[g] = __int_as_float(pb);
        }

        float x = Xb[cp][n8][t & 63];
        f32x2 xx = {x, x};
        f32x2 gi = f32x2{vA[0], vB[0]} + (xx * wg2[0] + bg2[0]);
        f32x2 gf = f32x2{vA[1], vB[1]} + (xx * wg2[1] + bg2[1]);
        f32x2 gg = f32x2{vA[2], vB[2]} + (xx * wg2[2] + bg2[2]);
        f32x2 go = f32x2{vA[3], vB[3]} + (xx * wg2[3] + bg2[3]);

        f32x2 si = sigf2(gi);
        f32x2 sf = sigf2(gf);
        f32x2 tg = tanh2(gg);
        f32x2 c0n2 = sf * c02 + si * tg;
        c02 = c0n2;
        f32x2 so = sigf2(go);
        f32x2 th = tanh2(c0n2);
        f32x2 h0n2 = so * th;

        unsigned hword  = cvt_pk_bf16(h0n2[0], h0n2[1]);
        unsigned chword = cvt_pk_bf16(c0n2[0], c0n2[1]);
        float hiA = bf2f(chword & 0xFFFFu);
        float hiB = bf2f(chword >> 16);
        f32x2 lo = c0n2 - f32x2{hiA, hiB};
        unsigned clword = cvt_pk_bf16(lo[0], lo[1]);
        const int widx = 8 * w + 2 * q16 + hi8;
        Hbuf[par ^ 1][0][n8][widx] = hword;
        Hbuf[par ^ 1][1][n8][widx] = chword;
        Hbuf[par ^ 1][2][n8][widx] = clword;

        if ((t & 63) == 63 && t + 1 < T_STEPS) {
            Xb[cp ^ 1][xr][xc]      = xnA;
            Xb[cp ^ 1][xr][xc + 32] = xnB;
        }

        step_barrier();
        par ^= 1;
    }

    if (w == 3) {
        const unsigned* Ch = &Hbuf[par][1][n16][0];
        const unsigned* Cl = &Hbuf[par][2][n16][0];
        short8 ch0 = *reinterpret_cast<const short8*>(Ch + 4 * q16);
        short8 ch1 = *reinterpret_cast<const short8*>(Ch + 16 + 4 * q16);
        short8 cl0 = *reinterpret_cast<const short8*>(Cl + 4 * q16);
        short8 cl1 = *reinterpret_cast<const short8*>(Cl + 16 + 4 * q16);
        float h1p = Lst[n8], c1p = Lst[8 + n8];
        f32x4 zA = {0.0f, 0.0f, 0.0f, 0.0f};
        f32x4 zB = {0.0f, 0.0f, 0.0f, 0.0f};
        zA = __builtin_amdgcn_mfma_f32_16x16x32_bf16(a2h[0], ch0, zA, 0, 0, 0);
        zB = __builtin_amdgcn_mfma_f32_16x16x32_bf16(a2l[1], ch1, zB, 0, 0, 0);
        zA = __builtin_amdgcn_mfma_f32_16x16x32_bf16(a2h[1], ch1, zA, 0, 0, 0);
        zB = __builtin_amdgcn_mfma_f32_16x16x32_bf16(a2h[0], cl0, zB, 0, 0, 0);
        zA = __builtin_amdgcn_mfma_f32_16x16x32_bf16(a2l[0], ch0, zA, 0, 0, 0);
        zB = __builtin_amdgcn_mfma_f32_16x16x32_bf16(a2h[1], cl1, zB, 0, 0, 0);
        f32x4 z = zA + zB;
        float g1i = z[0] + b1v[0] + h1p * whh1v[0];
        float g1f = z[1] + b1v[1] + h1p * whh1v[1];
        float g1g = z[2] + b1v[2] + h1p * whh1v[2];
        float g1o = z[3] + b1v[3] + h1p * whh1v[3];
        float c1n = sigf(g1f) * c1p + sigf(g1i) * tanh_fast(g1g);
        if (l < BTILE)
            out[(size_t)(bbase + l) * T_STEPS + (T_STEPS - 1)] = c1n;
    }
}

extern "C" void kernel_launch(void* const* d_in, const int* in_sizes, int n_in,
                              void* d_out, int out_size, void* d_ws, size_t ws_size,
                              hipStream_t stream) {
    const float* input = (const float*)d_in[0];
    const float* W_ih0 = (const float*)d_in[1];
    const float* W_hh0 = (const float*)d_in[2];
    const float* b_ih0 = (const float*)d_in[3];
    const float* b_hh0 = (const float*)d_in[4];
    const float* W_ih1 = (const float*)d_in[5];
    const float* W_hh1 = (const float*)d_in[6];
    const float* b_ih1 = (const float*)d_in[7];
    const float* b_hh1 = (const float*)d_in[8];
    float* out = (float*)d_out;

    const size_t g1_bytes = (size_t)BATCH * T_STEPS * 4 * sizeof(float);  // 32 MB
    if (ws_size >= g1_bytes && d_ws != nullptr) {
        float* g1ws = (float*)d_ws;
        lstm_v13_kernel<<<dim3(BATCH / BTILE), dim3(512), 0, stream>>>(
            input, W_ih0, W_hh0, b_ih0, b_hh0, W_ih1, g1ws);
        lstm_l2_kernel<<<dim3(BATCH / 64), dim3(64), 0, stream>>>(
            g1ws, W_hh1, b_ih1, b_hh1, out);
    } else {
        lstm_v11_kernel<<<dim3(BATCH / BTILE), dim3(256), 0, stream>>>(
            input, W_ih0, W_hh0, b_ih0, b_hh0, W_ih1, W_hh1, b_ih1, b_hh1, out);
    }
}

// Round 6
// 523.534 us; speedup vs baseline: 1.5071x; 1.5071x over previous
//
#include <hip/hip_runtime.h>

#define T_STEPS 1024
#define BATCH 2048
#define BTILE 8   // 8 batch rows/block -> 256 blocks -> 1 block/CU
#define HS 36     // LDS row stride in u32 words; 36 % 32 == 4 -> conflict-free b128 reads

typedef short short8 __attribute__((ext_vector_type(8)));
typedef float f32x4 __attribute__((ext_vector_type(4)));
typedef float f32x2 __attribute__((ext_vector_type(2)));

__device__ __forceinline__ float fast_rcp(float x) {
#if __has_builtin(__builtin_amdgcn_rcpf)
    return __builtin_amdgcn_rcpf(x);
#else
    return 1.0f / x;
#endif
}

__device__ __forceinline__ float fast_exp2(float x) {
#if __has_builtin(__builtin_amdgcn_exp2f)
    return __builtin_amdgcn_exp2f(x);
#else
    return exp2f(x);
#endif
}

__device__ __forceinline__ float sigf(float x) {
    return fast_rcp(1.0f + fast_exp2(-1.44269504f * x));
}

__device__ __forceinline__ f32x2 sigf2(f32x2 v) {
    f32x2 t = v * (-1.44269504f);
    f32x2 e = {fast_exp2(t[0]), fast_exp2(t[1])};
    e = e + 1.0f;
    return f32x2{fast_rcp(e[0]), fast_rcp(e[1])};
}

__device__ __forceinline__ float tanh_fast(float x) {
    float e = fast_exp2(2.88539008f * x);
    return 1.0f - 2.0f * fast_rcp(e + 1.0f);
}

__device__ __forceinline__ f32x2 tanh2(f32x2 v) {
    f32x2 t = v * 2.88539008f;
    f32x2 e = {fast_exp2(t[0]), fast_exp2(t[1])};
    e = e + 1.0f;
    f32x2 r = {fast_rcp(e[0]), fast_rcp(e[1])};
    return f32x2{1.0f, 1.0f} - 2.0f * r;
}

// float -> bf16 bits (RNE) — setup only
__device__ __forceinline__ unsigned f2bf(float x) {
    unsigned u = __float_as_uint(x);
    unsigned r = u + 0x7FFFu + ((u >> 16) & 1u);
    return r >> 16;
}

__device__ __forceinline__ unsigned cvt_pk_bf16(float a, float b) {
    unsigned r;
    asm("v_cvt_pk_bf16_f32 %0, %1, %2" : "=v"(r) : "v"(a), "v"(b));
    return r;
}

// Per-step barrier without the vmcnt(0) drain __syncthreads() emits.
// All in-loop cross-wave traffic is LDS (lgkmcnt(0)+s_barrier orders it);
// global ops are write-only stores / same-thread prefetch.
__device__ __forceinline__ void step_barrier() {
    asm volatile("s_waitcnt lgkmcnt(0)\n\ts_barrier" ::: "memory");
}

// ===================== v14: VALU-reduce L2 + in-kernel recurrence ===========
// v12's remaining structural costs: (a) the rotating duty wave's L2 shadow
// (4 ds_reads + 6 serial MFMAs + store) delayed EVERY step's barrier, and
// (b) a separate latency-bound l2 kernel (~150us). v14: the L2 GEMV is
// computed where c0n already lives — each thread does 8 FMAs (4 gates x 2
// units, exact f32), then a ds_swizzle butterfly (xor8, xor16) reduces over
// the 8 batch-sharing lanes per 32-lane half; the 2 half-partials per wave
// (8 per block) go to a 1KB LDS buffer. A DEDICATED 5th wave (320-thread
// block) sums the 8 partials one step behind, runs the serial L2 recurrence
// on 8 lanes, and scatter-stores c1n (L2 merges 16 same-line stores).
// Removes: duty skew, both c-planes of Hbuf, hi/lo c packing, the l2 kernel
// and its 32MB workspace. Single dispatch, no workspace needed.
__global__ __launch_bounds__(320, 1)
void lstm_v14_kernel(const float* __restrict__ input,
                     const float* __restrict__ W_ih0,
                     const float* __restrict__ W_hh0,
                     const float* __restrict__ b_ih0,
                     const float* __restrict__ b_hh0,
                     const float* __restrict__ W_ih1,
                     const float* __restrict__ W_hh1,
                     const float* __restrict__ b_ih1,
                     const float* __restrict__ b_hh1,
                     float* __restrict__ out)
{
    const int tid = threadIdx.x;
    const int w8  = tid >> 6;        // wave 0..3 = L1 compute, wave 4 = L2 recurrence
    const int l   = tid & 63;
    const int q16 = l >> 4;
    const int n16 = l & 15;
    const int n8  = l & 7;           // batch within block
    const int hi8 = n16 >> 3;
    const int ua  = 16 * w8 + 4 * q16 + 2 * hi8;   // even unit of thread's pair (w8<4)
    const int bbase = blockIdx.x * BTILE;

    __shared__ __align__(16) unsigned Hbuf[2][16][HS];   // h plane only, 4.6 KB
    __shared__ float Xb[2][BTILE][65];                   // 4.2 KB
    __shared__ __align__(16) f32x4 Pbuf[2][8][8];        // [par][pslot][batch] 1 KB

    for (int i = tid; i < 2 * 16 * HS; i += 320)
        reinterpret_cast<unsigned*>(Hbuf)[i] = 0u;

    // ---- L1 A-fragments (waves 0..3): a1[g][kt] = W_hh0 tile (w8+4g, kt) ----
    short8 a1[4][2];
    f32x2 wg2[4], bg2[4];
    float w1A[4], w1B[4];
    if (w8 < 4) {
        #pragma unroll
        for (int g = 0; g < 4; ++g) {
            #pragma unroll
            for (int kt = 0; kt < 2; ++kt) {
                const float* p = W_hh0 + (size_t)(16 * (w8 + 4 * g) + n16) * 64 + kt * 32 + q16 * 8;
                short8 a;
                #pragma unroll
                for (int j = 0; j < 8; ++j) a[j] = (short)f2bf(p[j]);
                a1[g][kt] = a;
            }
        }
        // activation constants for cell pair (units ua, ua+1)
        #pragma unroll
        for (int g = 0; g < 4; ++g) {
            int rA = g * 64 + ua;
            int rB = rA + 1;
            wg2[g] = f32x2{W_ih0[rA], W_ih0[rB]};
            bg2[g] = f32x2{b_ih0[rA] + b_hh0[rA], b_ih0[rB] + b_hh0[rB]};
            // L2 partial weights for this thread's units
            w1A[g] = W_ih1[g * 64 + ua];
            w1B[g] = W_ih1[g * 64 + ua + 1];
        }
    }
    // wave-4 recurrence constants (cheap for all waves to load)
    float wh1[4], bb1[4];
    #pragma unroll
    for (int g = 0; g < 4; ++g) { wh1[g] = W_hh1[g]; bb1[g] = b_ih1[g] + b_hh1[g]; }

    // ---- input staging: tid<256, thread (xr, xc) covers rows 0..7 x cols 0..63 ----
    const int xr = (tid >> 5) & 7;
    const int xc = tid & 31;
    const float* rowptr = input + (size_t)(bbase + xr) * T_STEPS;
    if (tid < 256) {
        Xb[0][xr][xc]      = rowptr[xc];
        Xb[0][xr][xc + 32] = rowptr[xc + 32];
    }
    float xnA = 0.0f, xnB = 0.0f;
    f32x2 c02 = {0.0f, 0.0f};
    float h1 = 0.0f, c1 = 0.0f;

    __syncthreads();

    int par = 0;
    #pragma unroll 2
    for (int t = 0; t < T_STEPS; ++t) {
        if (w8 < 4) {
            if ((t & 63) == 0 && t + 64 < T_STEPS) {
                xnA = rowptr[t + 64 + xc];
                xnB = rowptr[t + 64 + xc + 32];
            }
            const int cp = (t >> 6) & 1;

            // ---- B-fragments: h(t-1) ----
            const unsigned* Hrow = &Hbuf[par][n16][0];
            short8 hb0 = *reinterpret_cast<const short8*>(Hrow + 4 * q16);
            short8 hb1 = *reinterpret_cast<const short8*>(Hrow + 16 + 4 * q16);

            // ---- L1 MFMA ----
            f32x4 accv[4];
            #pragma unroll
            for (int g = 0; g < 4; ++g) {
                f32x4 z = {0.0f, 0.0f, 0.0f, 0.0f};
                z = __builtin_amdgcn_mfma_f32_16x16x32_bf16(a1[g][0], hb0, z, 0, 0, 0);
                z = __builtin_amdgcn_mfma_f32_16x16x32_bf16(a1[g][1], hb1, z, 0, 0, 0);
                accv[g] = z;
            }

            // ---- gate select (8 DPP serve the 2 cells) ----
            float vA[4], vB[4];
            #pragma unroll
            for (int g = 0; g < 4; ++g) {
                int pa = __float_as_int(accv[g][0]);
                pa = __builtin_amdgcn_update_dpp(pa, __float_as_int(accv[g][2]), 0x118, 0xf, 0xC, false);
                int pb = __float_as_int(accv[g][1]);
                pb = __builtin_amdgcn_update_dpp(pb, __float_as_int(accv[g][3]), 0x118, 0xf, 0xC, false);
                vA[g] = __int_as_float(pa);
                vB[g] = __int_as_float(pb);
            }

            // ---- layer-1 activation, 2 cells (batch n8, units ua/ua+1) ----
            float x = Xb[cp][n8][t & 63];
            f32x2 xx = {x, x};
            f32x2 gi = f32x2{vA[0], vB[0]} + (xx * wg2[0] + bg2[0]);
            f32x2 gf = f32x2{vA[1], vB[1]} + (xx * wg2[1] + bg2[1]);
            f32x2 gg = f32x2{vA[2], vB[2]} + (xx * wg2[2] + bg2[2]);
            f32x2 go = f32x2{vA[3], vB[3]} + (xx * wg2[3] + bg2[3]);

            f32x2 si = sigf2(gi);
            f32x2 sf = sigf2(gf);
            f32x2 tg = tanh2(gg);
            f32x2 c0n2 = sf * c02 + si * tg;
            c02 = c0n2;
            f32x2 so = sigf2(go);
            f32x2 th = tanh2(c0n2);
            f32x2 h0n2 = so * th;

            // ---- h pack + write (loop-carried) ----
            const int widx = 8 * w8 + 2 * q16 + hi8;
            Hbuf[par ^ 1][n8][widx] = cvt_pk_bf16(h0n2[0], h0n2[1]);

            // ---- L2 gate partials: 8 FMAs + xor8/xor16 butterfly ----
            float pg[4];
            #pragma unroll
            for (int g = 0; g < 4; ++g)
                pg[g] = w1A[g] * c0n2[0] + w1B[g] * c0n2[1];
            #pragma unroll
            for (int g = 0; g < 4; ++g) {
                float s = pg[g] + __int_as_float(
                    __builtin_amdgcn_ds_swizzle(__float_as_int(pg[g]), 0x201F));  // xor 8
                s = s + __int_as_float(
                    __builtin_amdgcn_ds_swizzle(__float_as_int(s), 0x401F));      // xor 16
                pg[g] = s;
            }
            if ((l & 31) < 8) {  // lanes 0..7 (lower 32 half) and 32..39 (upper)
                const int pslot = 2 * w8 + (l >> 5);
                Pbuf[par ^ 1][pslot][n8] = f32x4{pg[0], pg[1], pg[2], pg[3]};
            }

            if ((t & 63) == 63 && t + 1 < T_STEPS) {
                Xb[cp ^ 1][xr][xc]      = xnA;
                Xb[cp ^ 1][xr][xc + 32] = xnB;
            }
        } else {
            // ---- wave 4: L2 recurrence for step t-1 (8 independent lanes) ----
            if (t > 0 && l < 8) {
                f32x4 s = Pbuf[par][0][l];
                #pragma unroll
                for (int p = 1; p < 8; ++p) s += Pbuf[par][p][l];
                float gi = s[0] + bb1[0] + h1 * wh1[0];
                float gf = s[1] + bb1[1] + h1 * wh1[1];
                float gg = s[2] + bb1[2] + h1 * wh1[2];
                float go = s[3] + bb1[3] + h1 * wh1[3];
                float c1n = sigf(gf) * c1 + sigf(gi) * tanh_fast(gg);
                c1 = c1n;
                h1 = sigf(go) * tanh_fast(c1n);
                out[(size_t)(bbase + l) * T_STEPS + (t - 1)] = c1n;
            }
        }

        step_barrier();
        par ^= 1;
    }

    // ---- epilogue: L2 recurrence for step 1023 ----
    if (w8 == 4 && l < 8) {
        f32x4 s = Pbuf[par][0][l];
        #pragma unroll
        for (int p = 1; p < 8; ++p) s += Pbuf[par][p][l];
        float gi = s[0] + bb1[0] + h1 * wh1[0];
        float gf = s[1] + bb1[1] + h1 * wh1[1];
        float gg = s[2] + bb1[2] + h1 * wh1[2];
        float c1n = sigf(gf) * c1 + sigf(gi) * tanh_fast(gg);
        out[(size_t)(bbase + l) * T_STEPS + (T_STEPS - 1)] = c1n;
    }
}

extern "C" void kernel_launch(void* const* d_in, const int* in_sizes, int n_in,
                              void* d_out, int out_size, void* d_ws, size_t ws_size,
                              hipStream_t stream) {
    const float* input = (const float*)d_in[0];
    const float* W_ih0 = (const float*)d_in[1];
    const float* W_hh0 = (const float*)d_in[2];
    const float* b_ih0 = (const float*)d_in[3];
    const float* b_hh0 = (const float*)d_in[4];
    const float* W_ih1 = (const float*)d_in[5];
    const float* W_hh1 = (const float*)d_in[6];
    const float* b_ih1 = (const float*)d_in[7];
    const float* b_hh1 = (const float*)d_in[8];
    float* out = (float*)d_out;

    lstm_v14_kernel<<<dim3(BATCH / BTILE), dim3(320), 0, stream>>>(
        input, W_ih0, W_hh0, b_ih0, b_hh0, W_ih1, W_hh1, b_ih1, b_hh1, out);
}